// Round 5
// baseline (133.686 us; speedup 1.0000x reference)
//
#include <hip/hip_runtime.h>
#include <cstdint>
#include <cstddef>

typedef unsigned short u16;
typedef unsigned int u32;
typedef u16 u16x4 __attribute__((ext_vector_type(4)));
typedef u16 u16x8 __attribute__((ext_vector_type(8)));
typedef u32 u32x2 __attribute__((ext_vector_type(2)));
typedef u32 u32x4 __attribute__((ext_vector_type(4)));
typedef _Float16 f16x8 __attribute__((ext_vector_type(8)));
typedef float f32x4 __attribute__((ext_vector_type(4)));

#define B_   2
#define N_   2048
#define F_   512
#define D_   512
#define W_   128
#define E3   1536
#define MTOT 4096
#define QK_ELEMS (MTOT * D_) /* 2,097,152 */

/* ===== R14: DECOMPOSITION ROUND 2 =====
 * R13 measured gemm_marginal = 15.9 us (dur 94.5 -> 110.4 with GEMM x2).
 * This round: GEMM x1, attn x3 (idempotent: Out rewritten identically).
 *   A_marginal = (dur_us - 94.5) / 2
 * H_fast: A ~ 4-8 us -> dur ~102-110 -> window is fills/launch overhead,
 *         little kernel headroom left.
 * H_slow: A ~ 30-70 us -> dur ~155-235 -> attn is latency-pathological and
 *         becomes the sole optimization target.
 * Device code byte-identical to the passing R11 build. Remove next round. */

__device__ __forceinline__ u16 f2h(float f) {
  return __builtin_bit_cast(u16, (_Float16)f); /* v_cvt_f16_f32, RNE */
}
__device__ __forceinline__ u32 pk2h(float a, float b) {
  return __builtin_bit_cast(u32, __builtin_amdgcn_cvt_pkrtz(a, b));
}
__device__ __forceinline__ f32x4 mfma_f16(u16x8 a, u16x8 b, f32x4 c) {
  return __builtin_amdgcn_mfma_f32_16x16x32_f16(
      __builtin_bit_cast(f16x8, a), __builtin_bit_cast(f16x8, b), c, 0, 0, 0);
}

/* ---------------- QKV GEMM, fused fp32->fp16 reg-staged (R11) -------------- */
#define TM 128
#define TE 128
#define BK 32
#define NK (F_ / BK) /* 16 */

__global__ __launch_bounds__(256) void qkv_gemm(const float* __restrict__ X,
                                                const float* __restrict__ Wl,
                                                u16* __restrict__ Qf,
                                                u16* __restrict__ Kf,
                                                u16* __restrict__ Vt) {
  __shared__ __align__(16) u16 smem[16896]; /* dbuf 2x8192 u16; vbuf 4x8448 B */

  const int tid = threadIdx.x;
  const int m0 = blockIdx.x * TM;
  const int e0 = blockIdx.y * TE;
  const int lane = tid & 63;
  const int wave = tid >> 6;
  const int wm = (wave >> 1) * 64;
  const int we = (wave & 1) * 64;
  const int qd = lane >> 4;
  const int l16 = lane & 15;

  const int r0 = wave * 32;
  const int sr = lane >> 2; /* 0..15 */
  const int sc = lane & 3;  /* src chunk */
  const int key = (sr >> 1) & 3;
  const int cl = sc ^ key; /* LDS chunk */
  const int la = (r0 + sr) * 32 + cl * 8; /* u16 offset within a buffer half */

  const float* ga = X + (size_t)(m0 + r0 + sr) * F_ + sc * 8;
  const float* gb = Wl + (size_t)(e0 + r0 + sr) * F_ + sc * 8;

  f32x4 acc[4][4];
#pragma unroll
  for (int i = 0; i < 4; ++i)
#pragma unroll
    for (int j = 0; j < 4; ++j) acc[i][j] = (f32x4){0.f, 0.f, 0.f, 0.f};

  const int swz = (l16 >> 1) & 3;
  const int rdoff = (qd ^ swz) * 8; /* R6-proven read swizzle */

  /* Prologue: stage k=0 into buf0. */
  {
    float4 a0 = *(const float4*)(ga);
    float4 a1 = *(const float4*)(ga + 4);
    float4 a2 = *(const float4*)(ga + 16 * F_);
    float4 a3 = *(const float4*)(ga + 16 * F_ + 4);
    float4 b0 = *(const float4*)(gb);
    float4 b1 = *(const float4*)(gb + 4);
    float4 b2 = *(const float4*)(gb + 16 * F_);
    float4 b3 = *(const float4*)(gb + 16 * F_ + 4);
    u16* sA = smem;
    u16* sB = smem + 4096;
    *(u32x4*)&sA[la] = (u32x4){pk2h(a0.x, a0.y), pk2h(a0.z, a0.w),
                               pk2h(a1.x, a1.y), pk2h(a1.z, a1.w)};
    *(u32x4*)&sA[la + 512] = (u32x4){pk2h(a2.x, a2.y), pk2h(a2.z, a2.w),
                                     pk2h(a3.x, a3.y), pk2h(a3.z, a3.w)};
    *(u32x4*)&sB[la] = (u32x4){pk2h(b0.x, b0.y), pk2h(b0.z, b0.w),
                               pk2h(b1.x, b1.y), pk2h(b1.z, b1.w)};
    *(u32x4*)&sB[la + 512] = (u32x4){pk2h(b2.x, b2.y), pk2h(b2.z, b2.w),
                                     pk2h(b3.x, b3.y), pk2h(b3.z, b3.w)};
  }

  for (int k = 0; k < NK; ++k) {
    u16* sAk = smem + (k & 1) * 8192;
    u16* sBk = sAk + 4096;
    __syncthreads();

    u16x8 fA[4], fB[4];
#pragma unroll
    for (int mi = 0; mi < 4; ++mi)
      fA[mi] = *(const u16x8*)&sAk[(wm + mi * 16 + l16) * 32 + rdoff];
#pragma unroll
    for (int ei = 0; ei < 4; ++ei)
      fB[ei] = *(const u16x8*)&sBk[(we + ei * 16 + l16) * 32 + rdoff];

    /* Issue next tile's loads NOW; consumed after the MFMAs below. */
    float4 a0, a1, a2, a3, b0, b1, b2, b3;
    if (k + 1 < NK) {
      const float* gan = ga + (k + 1) * BK;
      const float* gbn = gb + (k + 1) * BK;
      a0 = *(const float4*)(gan);
      a1 = *(const float4*)(gan + 4);
      a2 = *(const float4*)(gan + 16 * F_);
      a3 = *(const float4*)(gan + 16 * F_ + 4);
      b0 = *(const float4*)(gbn);
      b1 = *(const float4*)(gbn + 4);
      b2 = *(const float4*)(gbn + 16 * F_);
      b3 = *(const float4*)(gbn + 16 * F_ + 4);
    }

#pragma unroll
    for (int mi = 0; mi < 4; ++mi)
#pragma unroll
      for (int ei = 0; ei < 4; ++ei)
        acc[mi][ei] = mfma_f16(fA[mi], fB[ei], acc[mi][ei]);

    if (k + 1 < NK) {
      u16* nA = smem + ((k + 1) & 1) * 8192;
      u16* nB = nA + 4096;
      *(u32x4*)&nA[la] = (u32x4){pk2h(a0.x, a0.y), pk2h(a0.z, a0.w),
                                 pk2h(a1.x, a1.y), pk2h(a1.z, a1.w)};
      *(u32x4*)&nA[la + 512] = (u32x4){pk2h(a2.x, a2.y), pk2h(a2.z, a2.w),
                                       pk2h(a3.x, a3.y), pk2h(a3.z, a3.w)};
      *(u32x4*)&nB[la] = (u32x4){pk2h(b0.x, b0.y), pk2h(b0.z, b0.w),
                                 pk2h(b1.x, b1.y), pk2h(b1.z, b1.w)};
      *(u32x4*)&nB[la + 512] = (u32x4){pk2h(b2.x, b2.y), pk2h(b2.z, b2.w),
                                       pk2h(b3.x, b3.y), pk2h(b3.z, b3.w)};
    }
  }

  /* C/D layout: row = qd*4 + reg, col = lane&15 */
  const int third = e0 >> 9; /* 0=Q, 1=K, 2=V */
  if (third < 2) {
    u16* P = third ? Kf : Qf;
    const int ecol0 = (e0 & 511) + we;
    const int odd = l16 & 1;
#pragma unroll
    for (int mi = 0; mi < 4; ++mi)
#pragma unroll
      for (int ei = 0; ei < 4; ++ei) {
        float x0 = acc[mi][ei][0], x1 = acc[mi][ei][1];
        float x2 = acc[mi][ei][2], x3 = acc[mi][ei][3];
        float t0 = __shfl_xor(x0, 1), t1 = __shfl_xor(x1, 1);
        float t2 = __shfl_xor(x2, 1), t3 = __shfl_xor(x3, 1);
        u32 pa = odd ? pk2h(t2, x2) : pk2h(x0, t0);
        u32 pb = odd ? pk2h(t3, x3) : pk2h(x1, t1);
        int mrow = m0 + wm + mi * 16 + qd * 4 + odd * 2;
        int colp = ecol0 + ei * 16 + (l16 & ~1);
        *(u32*)(P + (size_t)mrow * D_ + colp) = pa;
        *(u32*)(P + (size_t)(mrow + 1) * D_ + colp) = pb;
      }
  } else {
    /* V: per-wave 64x64 LDS transpose (stride 66 u16), coalesced Vt write. */
    __syncthreads();
    u16* vbuf = smem + wave * 4224; /* [64][66] u16 */
#pragma unroll
    for (int mi = 0; mi < 4; ++mi)
#pragma unroll
      for (int ei = 0; ei < 4; ++ei)
#pragma unroll
        for (int r2 = 0; r2 < 2; ++r2) {
          int e_in = ei * 16 + l16;
          int m_in = mi * 16 + qd * 4 + r2 * 2;
          u32 p = pk2h(acc[mi][ei][r2 * 2], acc[mi][ei][r2 * 2 + 1]);
          *(u32*)&vbuf[e_in * 66 + m_in] = p;
        }
    __builtin_amdgcn_s_waitcnt(0); /* drain lgkm before wave-local readback */
    const int dbase = (e0 - 1024) + we;
    const int mb = (m0 & 2047) + wm;
    const int bb = m0 >> 11;
    u16* vt = Vt + (size_t)bb * (D_ * N_);
#pragma unroll
    for (int it = 0; it < 4; ++it) {
      int e_in = it * 16 + (lane >> 2);
      int mc = lane & 3;
      u32 q0[8];
#pragma unroll
      for (int c4 = 0; c4 < 8; ++c4)
        q0[c4] = *(const u32*)&vbuf[e_in * 66 + mc * 16 + c4 * 2];
      u16* gp = vt + (size_t)(dbase + e_in) * N_ + mb + mc * 16;
      *(u32x4*)gp = (u32x4){q0[0], q0[1], q0[2], q0[3]};
      *(u32x4*)(gp + 8) = (u32x4){q0[4], q0[5], q0[6], q0[7]};
    }
  }
}

/* ---------------- MFMA sliding-window attention (R6-proven, R10-pruned) ---- */
#define TQA 16
#define SA 200
#define SP 208

__global__ __launch_bounds__(512) void attn_kernel(const u16* __restrict__ Qf,
                                                   const u16* __restrict__ Kf,
                                                   const u16* __restrict__ Vt,
                                                   float* __restrict__ Out) {
  const int m0 = blockIdx.x * TQA;
  const int b = m0 >> 11;
  const int n0 = m0 & 2047;
  const int t = threadIdx.x;
  const int lane = t & 63;
  const int w = t >> 6;
  const int qd = lane >> 4;
  const int l16 = lane & 15;

  __shared__ __align__(16) float att[2][TQA][SA];
  __shared__ __align__(16) u16 pS[TQA][SP];

  const int jw = w & 3;
  const int kh = w >> 2;
  const int ntm = (jw < 3) ? 3 : 1; /* col-tiles 0..9 only (160 cols) */

  /* Phase 1: logits = Q K^T, split-K across wave pairs. */
  f32x4 acc[3];
#pragma unroll
  for (int nt = 0; nt < 3; ++nt) acc[nt] = (f32x4){0.f, 0.f, 0.f, 0.f};

  const size_t qrow = (size_t)(m0 + l16) * D_ + qd * 8;
  for (int ks = kh * 8; ks < kh * 8 + 8; ++ks) {
    u16x8 qv = *(const u16x8*)(Qf + qrow + ks * 32);
#pragma unroll
    for (int nt = 0; nt < 3; ++nt) {
      if (nt < ntm) {
        int j = (jw * 3 + nt) * 16 + l16;
        int rl = n0 - 128 + j;
        int rg = b * N_ + (rl > 0 ? rl : 0);
        u16x8 kv = *(const u16x8*)(Kf + (size_t)rg * D_ + ks * 32 + qd * 8);
        acc[nt] = mfma_f16(qv, kv, acc[nt]);
      }
    }
  }
#pragma unroll
  for (int nt = 0; nt < 3; ++nt)
    if (nt < ntm) {
#pragma unroll
      for (int r = 0; r < 4; ++r)
        att[kh][qd * 4 + r][(jw * 3 + nt) * 16 + l16] = acc[nt][r];
    }
  __syncthreads();

  /* Phase 2: softmax per query i over j in [i+1, i+128]; 32 thr/row. */
  {
    const int i = t >> 5;
    const int c = t & 31;
    float ev[6];
    float mx = -1e30f;
#pragma unroll
    for (int s = 0; s < 6; ++s) {
      int j = c * 6 + s;
      bool inw = (j >= i + 1) && (j <= i + 128);
      float v = -1e30f;
      if (inw) v = (n0 - 128 + j < 0) ? 0.f : att[0][i][j] + att[1][i][j];
      ev[s] = v;
      mx = fmaxf(mx, v);
    }
    mx = fmaxf(mx, __shfl_xor(mx, 1));
    mx = fmaxf(mx, __shfl_xor(mx, 2));
    mx = fmaxf(mx, __shfl_xor(mx, 4));
    mx = fmaxf(mx, __shfl_xor(mx, 8));
    mx = fmaxf(mx, __shfl_xor(mx, 16));
    float sum = 0.f;
#pragma unroll
    for (int s = 0; s < 6; ++s) {
      ev[s] = (ev[s] > -1e29f) ? __expf(ev[s] - mx) : 0.f;
      sum += ev[s];
    }
    sum += __shfl_xor(sum, 1);
    sum += __shfl_xor(sum, 2);
    sum += __shfl_xor(sum, 4);
    sum += __shfl_xor(sum, 8);
    sum += __shfl_xor(sum, 16);
    const float inv = 1.f / sum;
#pragma unroll
    for (int s = 0; s < 6; ++s) {
      int j = c * 6 + s;
      bool zv = (n0 - 128 + j) < 0;
      pS[i][j] = zv ? (u16)0 : f2h(ev[s] * inv);
    }
  }
  __syncthreads();

  /* Phase 3: Out = P V; wave w owns d-cols [w*64, w*64+64). kk<5. */
  f32x4 oacc[4];
#pragma unroll
  for (int nt = 0; nt < 4; ++nt) oacc[nt] = (f32x4){0.f, 0.f, 0.f, 0.f};

  const u16* vtb = Vt + (size_t)b * (D_ * N_);
  for (int kk = 0; kk < 5; ++kk) {
    u16x8 pa = *(const u16x8*)&pS[l16][kk * 32 + qd * 8];
    const int rl = n0 - 128 + kk * 32 + qd * 8; /* may be <0: P=0 guards */
#pragma unroll
    for (int nt = 0; nt < 4; ++nt) {
      int d = w * 64 + nt * 16 + l16;
      u16x8 vv = *(const u16x8*)(vtb + (size_t)d * N_ + rl);
      oacc[nt] = mfma_f16(pa, vv, oacc[nt]);
    }
  }
#pragma unroll
  for (int nt = 0; nt < 4; ++nt)
#pragma unroll
    for (int r = 0; r < 4; ++r)
      Out[(size_t)(m0 + qd * 4 + r) * D_ + w * 64 + nt * 16 + l16] = oacc[nt][r];
}

extern "C" void kernel_launch(void* const* d_in, const int* in_sizes, int n_in,
                              void* d_out, int out_size, void* d_ws, size_t ws_size,
                              hipStream_t stream) {
  const float* x = (const float*)d_in[0];
  const float* wl = (const float*)d_in[1];
  float* out = (float*)d_out;

  u16* Qf = (u16*)d_ws;
  u16* Kf = Qf + QK_ELEMS;
  u16* Vt = Kf + QK_ELEMS;

  dim3 g1(MTOT / TM, E3 / TE); /* 32 x 12 */
  qkv_gemm<<<g1, 256, 0, stream>>>(x, wl, Qf, Kf, Vt);
  /* R14 decomposition: triple-launch the (idempotent) attention kernel.
   * A_marginal = (dur_us - 94.5) / 2. Remove next round. */
  attn_kernel<<<MTOT / TQA, 512, 0, stream>>>(Qf, Kf, Vt, out);
  attn_kernel<<<MTOT / TQA, 512, 0, stream>>>(Qf, Kf, Vt, out);
  attn_kernel<<<MTOT / TQA, 512, 0, stream>>>(Qf, Kf, Vt, out);
}

// Round 6
// 100.784 us; speedup vs baseline: 1.3265x; 1.3265x over previous
//
#include <hip/hip_runtime.h>
#include <cstdint>
#include <cstddef>

typedef unsigned short u16;
typedef unsigned int u32;
typedef u16 u16x4 __attribute__((ext_vector_type(4)));
typedef u16 u16x8 __attribute__((ext_vector_type(8)));
typedef u32 u32x2 __attribute__((ext_vector_type(2)));
typedef u32 u32x4 __attribute__((ext_vector_type(4)));
typedef _Float16 f16x8 __attribute__((ext_vector_type(8)));
typedef float f32x4 __attribute__((ext_vector_type(4)));

#define B_   2
#define N_   2048
#define F_   512
#define D_   512
#define W_   128
#define E3   1536
#define MTOT 4096
#define QK_ELEMS (MTOT * D_) /* 2,097,152 */

/* ===== R15 =====
 * Decomposition (R13/R14): gemm ~15.9 us, attn ~19.6 us, launch gaps ~0,
 * rest of the 94.5 us window = harness poison-fill + fixed overhead.
 * attn was 1 block/CU (256 blocks) -> latency-bound at ~4x its BW floor.
 * This round: attn TQA 16 -> 8 => 512 blocks = 2 blocks/CU, 16 waves/CU.
 *  - window union per 8-query block: j in [1,135] -> 9 col-tiles (was 10/16q)
 *  - phase 2: one wave per query row, 64-lane shfl reduce
 *  - pS padded to 16 rows (8..15 zeroed) so phase-3 MFMA A-operand is safe
 *  - LDS ~15 KB, __launch_bounds__(512,4) (VGPR<=128) => 2 blocks/CU
 * GEMM byte-identical to the passing R11 build (rebalance queued next). */

__device__ __forceinline__ u16 f2h(float f) {
  return __builtin_bit_cast(u16, (_Float16)f); /* v_cvt_f16_f32, RNE */
}
__device__ __forceinline__ u32 pk2h(float a, float b) {
  return __builtin_bit_cast(u32, __builtin_amdgcn_cvt_pkrtz(a, b));
}
__device__ __forceinline__ f32x4 mfma_f16(u16x8 a, u16x8 b, f32x4 c) {
  return __builtin_amdgcn_mfma_f32_16x16x32_f16(
      __builtin_bit_cast(f16x8, a), __builtin_bit_cast(f16x8, b), c, 0, 0, 0);
}

/* ---------------- QKV GEMM, fused fp32->fp16 reg-staged (R11) -------------- */
#define TM 128
#define TE 128
#define BK 32
#define NK (F_ / BK) /* 16 */

__global__ __launch_bounds__(256) void qkv_gemm(const float* __restrict__ X,
                                                const float* __restrict__ Wl,
                                                u16* __restrict__ Qf,
                                                u16* __restrict__ Kf,
                                                u16* __restrict__ Vt) {
  __shared__ __align__(16) u16 smem[16896]; /* dbuf 2x8192 u16; vbuf 4x8448 B */

  const int tid = threadIdx.x;
  const int m0 = blockIdx.x * TM;
  const int e0 = blockIdx.y * TE;
  const int lane = tid & 63;
  const int wave = tid >> 6;
  const int wm = (wave >> 1) * 64;
  const int we = (wave & 1) * 64;
  const int qd = lane >> 4;
  const int l16 = lane & 15;

  const int r0 = wave * 32;
  const int sr = lane >> 2; /* 0..15 */
  const int sc = lane & 3;  /* src chunk */
  const int key = (sr >> 1) & 3;
  const int cl = sc ^ key; /* LDS chunk */
  const int la = (r0 + sr) * 32 + cl * 8; /* u16 offset within a buffer half */

  const float* ga = X + (size_t)(m0 + r0 + sr) * F_ + sc * 8;
  const float* gb = Wl + (size_t)(e0 + r0 + sr) * F_ + sc * 8;

  f32x4 acc[4][4];
#pragma unroll
  for (int i = 0; i < 4; ++i)
#pragma unroll
    for (int j = 0; j < 4; ++j) acc[i][j] = (f32x4){0.f, 0.f, 0.f, 0.f};

  const int swz = (l16 >> 1) & 3;
  const int rdoff = (qd ^ swz) * 8; /* R6-proven read swizzle */

  /* Prologue: stage k=0 into buf0. */
  {
    float4 a0 = *(const float4*)(ga);
    float4 a1 = *(const float4*)(ga + 4);
    float4 a2 = *(const float4*)(ga + 16 * F_);
    float4 a3 = *(const float4*)(ga + 16 * F_ + 4);
    float4 b0 = *(const float4*)(gb);
    float4 b1 = *(const float4*)(gb + 4);
    float4 b2 = *(const float4*)(gb + 16 * F_);
    float4 b3 = *(const float4*)(gb + 16 * F_ + 4);
    u16* sA = smem;
    u16* sB = smem + 4096;
    *(u32x4*)&sA[la] = (u32x4){pk2h(a0.x, a0.y), pk2h(a0.z, a0.w),
                               pk2h(a1.x, a1.y), pk2h(a1.z, a1.w)};
    *(u32x4*)&sA[la + 512] = (u32x4){pk2h(a2.x, a2.y), pk2h(a2.z, a2.w),
                                     pk2h(a3.x, a3.y), pk2h(a3.z, a3.w)};
    *(u32x4*)&sB[la] = (u32x4){pk2h(b0.x, b0.y), pk2h(b0.z, b0.w),
                               pk2h(b1.x, b1.y), pk2h(b1.z, b1.w)};
    *(u32x4*)&sB[la + 512] = (u32x4){pk2h(b2.x, b2.y), pk2h(b2.z, b2.w),
                                     pk2h(b3.x, b3.y), pk2h(b3.z, b3.w)};
  }

  for (int k = 0; k < NK; ++k) {
    u16* sAk = smem + (k & 1) * 8192;
    u16* sBk = sAk + 4096;
    __syncthreads();

    u16x8 fA[4], fB[4];
#pragma unroll
    for (int mi = 0; mi < 4; ++mi)
      fA[mi] = *(const u16x8*)&sAk[(wm + mi * 16 + l16) * 32 + rdoff];
#pragma unroll
    for (int ei = 0; ei < 4; ++ei)
      fB[ei] = *(const u16x8*)&sBk[(we + ei * 16 + l16) * 32 + rdoff];

    /* Issue next tile's loads NOW; consumed after the MFMAs below. */
    float4 a0, a1, a2, a3, b0, b1, b2, b3;
    if (k + 1 < NK) {
      const float* gan = ga + (k + 1) * BK;
      const float* gbn = gb + (k + 1) * BK;
      a0 = *(const float4*)(gan);
      a1 = *(const float4*)(gan + 4);
      a2 = *(const float4*)(gan + 16 * F_);
      a3 = *(const float4*)(gan + 16 * F_ + 4);
      b0 = *(const float4*)(gbn);
      b1 = *(const float4*)(gbn + 4);
      b2 = *(const float4*)(gbn + 16 * F_);
      b3 = *(const float4*)(gbn + 16 * F_ + 4);
    }

#pragma unroll
    for (int mi = 0; mi < 4; ++mi)
#pragma unroll
      for (int ei = 0; ei < 4; ++ei)
        acc[mi][ei] = mfma_f16(fA[mi], fB[ei], acc[mi][ei]);

    if (k + 1 < NK) {
      u16* nA = smem + ((k + 1) & 1) * 8192;
      u16* nB = nA + 4096;
      *(u32x4*)&nA[la] = (u32x4){pk2h(a0.x, a0.y), pk2h(a0.z, a0.w),
                                 pk2h(a1.x, a1.y), pk2h(a1.z, a1.w)};
      *(u32x4*)&nA[la + 512] = (u32x4){pk2h(a2.x, a2.y), pk2h(a2.z, a2.w),
                                       pk2h(a3.x, a3.y), pk2h(a3.z, a3.w)};
      *(u32x4*)&nB[la] = (u32x4){pk2h(b0.x, b0.y), pk2h(b0.z, b0.w),
                                 pk2h(b1.x, b1.y), pk2h(b1.z, b1.w)};
      *(u32x4*)&nB[la + 512] = (u32x4){pk2h(b2.x, b2.y), pk2h(b2.z, b2.w),
                                       pk2h(b3.x, b3.y), pk2h(b3.z, b3.w)};
    }
  }

  /* C/D layout: row = qd*4 + reg, col = lane&15 */
  const int third = e0 >> 9; /* 0=Q, 1=K, 2=V */
  if (third < 2) {
    u16* P = third ? Kf : Qf;
    const int ecol0 = (e0 & 511) + we;
    const int odd = l16 & 1;
#pragma unroll
    for (int mi = 0; mi < 4; ++mi)
#pragma unroll
      for (int ei = 0; ei < 4; ++ei) {
        float x0 = acc[mi][ei][0], x1 = acc[mi][ei][1];
        float x2 = acc[mi][ei][2], x3 = acc[mi][ei][3];
        float t0 = __shfl_xor(x0, 1), t1 = __shfl_xor(x1, 1);
        float t2 = __shfl_xor(x2, 1), t3 = __shfl_xor(x3, 1);
        u32 pa = odd ? pk2h(t2, x2) : pk2h(x0, t0);
        u32 pb = odd ? pk2h(t3, x3) : pk2h(x1, t1);
        int mrow = m0 + wm + mi * 16 + qd * 4 + odd * 2;
        int colp = ecol0 + ei * 16 + (l16 & ~1);
        *(u32*)(P + (size_t)mrow * D_ + colp) = pa;
        *(u32*)(P + (size_t)(mrow + 1) * D_ + colp) = pb;
      }
  } else {
    /* V: per-wave 64x64 LDS transpose (stride 66 u16), coalesced Vt write. */
    __syncthreads();
    u16* vbuf = smem + wave * 4224; /* [64][66] u16 */
#pragma unroll
    for (int mi = 0; mi < 4; ++mi)
#pragma unroll
      for (int ei = 0; ei < 4; ++ei)
#pragma unroll
        for (int r2 = 0; r2 < 2; ++r2) {
          int e_in = ei * 16 + l16;
          int m_in = mi * 16 + qd * 4 + r2 * 2;
          u32 p = pk2h(acc[mi][ei][r2 * 2], acc[mi][ei][r2 * 2 + 1]);
          *(u32*)&vbuf[e_in * 66 + m_in] = p;
        }
    __builtin_amdgcn_s_waitcnt(0); /* drain lgkm before wave-local readback */
    const int dbase = (e0 - 1024) + we;
    const int mb = (m0 & 2047) + wm;
    const int bb = m0 >> 11;
    u16* vt = Vt + (size_t)bb * (D_ * N_);
#pragma unroll
    for (int it = 0; it < 4; ++it) {
      int e_in = it * 16 + (lane >> 2);
      int mc = lane & 3;
      u32 q0[8];
#pragma unroll
      for (int c4 = 0; c4 < 8; ++c4)
        q0[c4] = *(const u32*)&vbuf[e_in * 66 + mc * 16 + c4 * 2];
      u16* gp = vt + (size_t)(dbase + e_in) * N_ + mb + mc * 16;
      *(u32x4*)gp = (u32x4){q0[0], q0[1], q0[2], q0[3]};
      *(u32x4*)(gp + 8) = (u32x4){q0[4], q0[5], q0[6], q0[7]};
    }
  }
}

/* ---------------- MFMA sliding-window attention (R15: TQA=8, 2 blocks/CU) --
 * 512 blocks x 512 threads (8 waves). Queries per block: 8 (rows m0..m0+7).
 * Window union: j in [1,135] -> 9 col-tiles of 16 (cols 0..143).
 * Phase 1: split-K (kh = w>>2, 2 halves) x col-split (jw = w&3);
 *   tile tt = nt*4 + jw for nt < ntm (ntm = 3 for jw==0 else 2) -> tiles 0..8.
 *   MFMA computes 16 query rows; rows 8..15 are discarded (qd<2 stores).
 * Phase 2: wave w owns query row w; 64-lane shfl reduce; cols j = lane+64s.
 *   pS rows 8..15 zeroed (phase 3 A-operand reads 16 rows).
 * Phase 3: unchanged: wave owns 64 d-cols, kk<5 covers P cols 0..159.
 * Zero-pad rows (rl<0): logit 0.0 in the denominator, P forced 0 (R6). */
#define TQA 8
#define SA 152 /* att cols pad (144 used) */
#define SP 168 /* pS cols pad (160 used) */

__global__ __launch_bounds__(512, 4) void attn_kernel(const u16* __restrict__ Qf,
                                                      const u16* __restrict__ Kf,
                                                      const u16* __restrict__ Vt,
                                                      float* __restrict__ Out) {
  const int m0 = blockIdx.x * TQA;
  const int b = m0 >> 11;
  const int n0 = m0 & 2047;
  const int t = threadIdx.x;
  const int lane = t & 63;
  const int w = t >> 6;
  const int qd = lane >> 4;
  const int l16 = lane & 15;

  __shared__ __align__(16) float att[2][TQA][SA];
  __shared__ __align__(16) u16 pS[16][SP];

  const int jw = w & 3;
  const int kh = w >> 2;
  const int ntm = (jw == 0) ? 3 : 2; /* 9 tiles: jw0 -> {0,4,8}, jwX -> {X,X+4} */

  /* Phase 1: logits = Q K^T, split-K across wave pairs. */
  f32x4 acc[3];
#pragma unroll
  for (int nt = 0; nt < 3; ++nt) acc[nt] = (f32x4){0.f, 0.f, 0.f, 0.f};

  /* Q rows m0..m0+15; rows >= 8 are the next block's (or OOB-into-Kf for the
   * last block) -- results discarded, memory-safe. */
  const size_t qrow = (size_t)(m0 + l16) * D_ + qd * 8;
  for (int ks = kh * 8; ks < kh * 8 + 8; ++ks) {
    u16x8 qv = *(const u16x8*)(Qf + qrow + ks * 32);
#pragma unroll
    for (int nt = 0; nt < 3; ++nt) {
      if (nt < ntm) {
        int j = (nt * 4 + jw) * 16 + l16;
        int rl = n0 - 128 + j;
        int rg = b * N_ + (rl > 0 ? rl : 0);
        u16x8 kv = *(const u16x8*)(Kf + (size_t)rg * D_ + ks * 32 + qd * 8);
        acc[nt] = mfma_f16(qv, kv, acc[nt]);
      }
    }
  }
#pragma unroll
  for (int nt = 0; nt < 3; ++nt)
    if (nt < ntm && qd < 2) { /* keep query rows 0..7 only */
#pragma unroll
      for (int r = 0; r < 4; ++r)
        att[kh][qd * 4 + r][(nt * 4 + jw) * 16 + l16] = acc[nt][r];
    }
  __syncthreads();

  /* Phase 2: softmax; wave w owns query row i=w; 64 lanes, 3 cols each. */
  {
    const int i = w;
    const int c = lane;
    float ev[3];
    float mx = -1e30f;
#pragma unroll
    for (int s = 0; s < 3; ++s) {
      int j = c + s * 64;
      bool inw = (j >= i + 1) && (j <= i + 128);
      float v = -1e30f;
      if (inw) v = (n0 - 128 + j < 0) ? 0.f : att[0][i][j] + att[1][i][j];
      ev[s] = v;
      mx = fmaxf(mx, v);
    }
    mx = fmaxf(mx, __shfl_xor(mx, 1));
    mx = fmaxf(mx, __shfl_xor(mx, 2));
    mx = fmaxf(mx, __shfl_xor(mx, 4));
    mx = fmaxf(mx, __shfl_xor(mx, 8));
    mx = fmaxf(mx, __shfl_xor(mx, 16));
    mx = fmaxf(mx, __shfl_xor(mx, 32));
    float sum = 0.f;
#pragma unroll
    for (int s = 0; s < 3; ++s) {
      ev[s] = (ev[s] > -1e29f) ? __expf(ev[s] - mx) : 0.f;
      sum += ev[s];
    }
    sum += __shfl_xor(sum, 1);
    sum += __shfl_xor(sum, 2);
    sum += __shfl_xor(sum, 4);
    sum += __shfl_xor(sum, 8);
    sum += __shfl_xor(sum, 16);
    sum += __shfl_xor(sum, 32);
    const float inv = 1.f / sum;
#pragma unroll
    for (int s = 0; s < 3; ++s) {
      int j = c + s * 64;
      if (j < 160) {
        bool zv = (n0 - 128 + j) < 0;
        pS[i][j] = zv ? (u16)0 : f2h(ev[s] * inv);
        pS[i + 8][j] = (u16)0; /* zero rows 8..15 for the phase-3 A-operand */
      }
    }
  }
  __syncthreads();

  /* Phase 3: Out = P V; wave w owns d-cols [w*64, w*64+64). kk<5. */
  f32x4 oacc[4];
#pragma unroll
  for (int nt = 0; nt < 4; ++nt) oacc[nt] = (f32x4){0.f, 0.f, 0.f, 0.f};

  const u16* vtb = Vt + (size_t)b * (D_ * N_);
  for (int kk = 0; kk < 5; ++kk) {
    u16x8 pa = *(const u16x8*)&pS[l16][kk * 32 + qd * 8];
    const int rl = n0 - 128 + kk * 32 + qd * 8; /* may be <0: P=0 guards */
#pragma unroll
    for (int nt = 0; nt < 4; ++nt) {
      int d = w * 64 + nt * 16 + l16;
      u16x8 vv = *(const u16x8*)(vtb + (size_t)d * N_ + rl);
      oacc[nt] = mfma_f16(pa, vv, oacc[nt]);
    }
  }
  if (qd < 2) {
#pragma unroll
    for (int nt = 0; nt < 4; ++nt)
#pragma unroll
      for (int r = 0; r < 4; ++r)
        Out[(size_t)(m0 + qd * 4 + r) * D_ + w * 64 + nt * 16 + l16] = oacc[nt][r];
  }
}

extern "C" void kernel_launch(void* const* d_in, const int* in_sizes, int n_in,
                              void* d_out, int out_size, void* d_ws, size_t ws_size,
                              hipStream_t stream) {
  const float* x = (const float*)d_in[0];
  const float* wl = (const float*)d_in[1];
  float* out = (float*)d_out;

  u16* Qf = (u16*)d_ws;
  u16* Kf = Qf + QK_ELEMS;
  u16* Vt = Kf + QK_ELEMS;

  dim3 g1(MTOT / TM, E3 / TE); /* 32 x 12 */
  qkv_gemm<<<g1, 256, 0, stream>>>(x, wl, Qf, Kf, Vt);
  attn_kernel<<<MTOT / TQA, 512, 0, stream>>>(Qf, Kf, Vt, out);
}

// Round 7
// 97.295 us; speedup vs baseline: 1.3740x; 1.0359x over previous
//
#include <hip/hip_runtime.h>
#include <cstdint>
#include <cstddef>

typedef unsigned short u16;
typedef unsigned int u32;
typedef u16 u16x4 __attribute__((ext_vector_type(4)));
typedef u16 u16x8 __attribute__((ext_vector_type(8)));
typedef u32 u32x2 __attribute__((ext_vector_type(2)));
typedef u32 u32x4 __attribute__((ext_vector_type(4)));
typedef _Float16 f16x8 __attribute__((ext_vector_type(8)));
typedef float f32x4 __attribute__((ext_vector_type(4)));

#define B_   2
#define N_   2048
#define F_   512
#define D_   512
#define W_   128
#define E3   1536
#define MTOT 4096
#define QK_ELEMS (MTOT * D_) /* 2,097,152 */

/* ===== R16 =====
 * R15 post-mortem: TQA=8 attn REGRESSED (attn 19.6 -> ~26 us): the sliding
 * window (~TQA+128 cols) doesn't shrink with the Q-tile, so halving TQA
 * doubled total K-fetch + MFMA work. Reverted attn to the R11 TQA=16 kernel.
 * New single variable: GEMM prefetch depth 1 -> 2. The poison-fill wipes L2
 * every iteration, so K-loop loads are cold-HBM (~900cy); R11 hid them under
 * only ~1 MFMA block. Now tile k+2's loads are issued at iter k and stored
 * at iter k+1 -> a full iteration (barrier+ds_read+16 MFMA+ds_write) covers
 * each load. Full unroll keeps reg-tile indexing static (no scratch). */

__device__ __forceinline__ u16 f2h(float f) {
  return __builtin_bit_cast(u16, (_Float16)f); /* v_cvt_f16_f32, RNE */
}
__device__ __forceinline__ u32 pk2h(float a, float b) {
  return __builtin_bit_cast(u32, __builtin_amdgcn_cvt_pkrtz(a, b));
}
__device__ __forceinline__ f32x4 mfma_f16(u16x8 a, u16x8 b, f32x4 c) {
  return __builtin_amdgcn_mfma_f32_16x16x32_f16(
      __builtin_bit_cast(f16x8, a), __builtin_bit_cast(f16x8, b), c, 0, 0, 0);
}

/* ---------------- QKV GEMM, fp32->fp16 reg-staged, 2-deep prefetch --------- */
#define TM 128
#define TE 128
#define BK 32
#define NK (F_ / BK) /* 16 */

struct Tile {
  float4 a0, a1, a2, a3, b0, b1, b2, b3;
};

__global__ __launch_bounds__(256) void qkv_gemm(const float* __restrict__ X,
                                                const float* __restrict__ Wl,
                                                u16* __restrict__ Qf,
                                                u16* __restrict__ Kf,
                                                u16* __restrict__ Vt) {
  __shared__ __align__(16) u16 smem[16896]; /* dbuf 2x8192 u16; vbuf 4x8448 B */

  const int tid = threadIdx.x;
  const int m0 = blockIdx.x * TM;
  const int e0 = blockIdx.y * TE;
  const int lane = tid & 63;
  const int wave = tid >> 6;
  const int wm = (wave >> 1) * 64;
  const int we = (wave & 1) * 64;
  const int qd = lane >> 4;
  const int l16 = lane & 15;

  const int r0 = wave * 32;
  const int sr = lane >> 2; /* 0..15 */
  const int sc = lane & 3;  /* src chunk */
  const int key = (sr >> 1) & 3;
  const int cl = sc ^ key; /* LDS chunk */
  const int la = (r0 + sr) * 32 + cl * 8; /* u16 offset within a buffer half */

  const float* ga = X + (size_t)(m0 + r0 + sr) * F_ + sc * 8;
  const float* gb = Wl + (size_t)(e0 + r0 + sr) * F_ + sc * 8;

  f32x4 acc[4][4];
#pragma unroll
  for (int i = 0; i < 4; ++i)
#pragma unroll
    for (int j = 0; j < 4; ++j) acc[i][j] = (f32x4){0.f, 0.f, 0.f, 0.f};

  const int swz = (l16 >> 1) & 3;
  const int rdoff = (qd ^ swz) * 8; /* R6-proven read swizzle */

  Tile tr[2];

  /* Prologue: load tiles 0,1 into regs; stage tile 0 into buf0. */
#define LOAD_TILE(T, KT)                                                       \
  do {                                                                         \
    const float* gan = ga + (KT) * BK;                                         \
    const float* gbn = gb + (KT) * BK;                                         \
    (T).a0 = *(const float4*)(gan);                                            \
    (T).a1 = *(const float4*)(gan + 4);                                        \
    (T).a2 = *(const float4*)(gan + 16 * F_);                                  \
    (T).a3 = *(const float4*)(gan + 16 * F_ + 4);                              \
    (T).b0 = *(const float4*)(gbn);                                            \
    (T).b1 = *(const float4*)(gbn + 4);                                        \
    (T).b2 = *(const float4*)(gbn + 16 * F_);                                  \
    (T).b3 = *(const float4*)(gbn + 16 * F_ + 4);                              \
  } while (0)

#define STORE_TILE(BUF, T)                                                     \
  do {                                                                         \
    u16* nA = (BUF);                                                           \
    u16* nB = (BUF) + 4096;                                                    \
    *(u32x4*)&nA[la] = (u32x4){pk2h((T).a0.x, (T).a0.y), pk2h((T).a0.z, (T).a0.w), \
                               pk2h((T).a1.x, (T).a1.y), pk2h((T).a1.z, (T).a1.w)}; \
    *(u32x4*)&nA[la + 512] = (u32x4){pk2h((T).a2.x, (T).a2.y), pk2h((T).a2.z, (T).a2.w), \
                                     pk2h((T).a3.x, (T).a3.y), pk2h((T).a3.z, (T).a3.w)}; \
    *(u32x4*)&nB[la] = (u32x4){pk2h((T).b0.x, (T).b0.y), pk2h((T).b0.z, (T).b0.w), \
                               pk2h((T).b1.x, (T).b1.y), pk2h((T).b1.z, (T).b1.w)}; \
    *(u32x4*)&nB[la + 512] = (u32x4){pk2h((T).b2.x, (T).b2.y), pk2h((T).b2.z, (T).b2.w), \
                                     pk2h((T).b3.x, (T).b3.y), pk2h((T).b3.z, (T).b3.w)}; \
  } while (0)

  LOAD_TILE(tr[0], 0);
  LOAD_TILE(tr[1], 1);
  STORE_TILE(smem, tr[0]);

#pragma unroll
  for (int k = 0; k < NK; ++k) {
    u16* sAk = smem + (k & 1) * 8192;
    u16* sBk = sAk + 4096;
    __syncthreads();

    u16x8 fA[4], fB[4];
#pragma unroll
    for (int mi = 0; mi < 4; ++mi)
      fA[mi] = *(const u16x8*)&sAk[(wm + mi * 16 + l16) * 32 + rdoff];
#pragma unroll
    for (int ei = 0; ei < 4; ++ei)
      fB[ei] = *(const u16x8*)&sBk[(we + ei * 16 + l16) * 32 + rdoff];

    /* 2-deep prefetch: issue tile k+2's loads now (into the reg set whose
     * tile k was staged last iteration); consumed (stored) next iteration. */
    if (k + 2 < NK) LOAD_TILE(tr[k & 1], k + 2);

#pragma unroll
    for (int mi = 0; mi < 4; ++mi)
#pragma unroll
      for (int ei = 0; ei < 4; ++ei)
        acc[mi][ei] = mfma_f16(fA[mi], fB[ei], acc[mi][ei]);

    /* Stage tile k+1 (loaded two iterations ago; latency fully covered).
     * buf[(k+1)&1] was last READ at iter k-1; the barrier above fences it. */
    if (k + 1 < NK) STORE_TILE(smem + ((k + 1) & 1) * 8192, tr[(k + 1) & 1]);
  }

  /* C/D layout: row = qd*4 + reg, col = lane&15 */
  const int third = e0 >> 9; /* 0=Q, 1=K, 2=V */
  if (third < 2) {
    u16* P = third ? Kf : Qf;
    const int ecol0 = (e0 & 511) + we;
    const int odd = l16 & 1;
#pragma unroll
    for (int mi = 0; mi < 4; ++mi)
#pragma unroll
      for (int ei = 0; ei < 4; ++ei) {
        float x0 = acc[mi][ei][0], x1 = acc[mi][ei][1];
        float x2 = acc[mi][ei][2], x3 = acc[mi][ei][3];
        float t0 = __shfl_xor(x0, 1), t1 = __shfl_xor(x1, 1);
        float t2 = __shfl_xor(x2, 1), t3 = __shfl_xor(x3, 1);
        u32 pa = odd ? pk2h(t2, x2) : pk2h(x0, t0);
        u32 pb = odd ? pk2h(t3, x3) : pk2h(x1, t1);
        int mrow = m0 + wm + mi * 16 + qd * 4 + odd * 2;
        int colp = ecol0 + ei * 16 + (l16 & ~1);
        *(u32*)(P + (size_t)mrow * D_ + colp) = pa;
        *(u32*)(P + (size_t)(mrow + 1) * D_ + colp) = pb;
      }
  } else {
    /* V: per-wave 64x64 LDS transpose (stride 66 u16), coalesced Vt write. */
    __syncthreads();
    u16* vbuf = smem + wave * 4224; /* [64][66] u16 */
#pragma unroll
    for (int mi = 0; mi < 4; ++mi)
#pragma unroll
      for (int ei = 0; ei < 4; ++ei)
#pragma unroll
        for (int r2 = 0; r2 < 2; ++r2) {
          int e_in = ei * 16 + l16;
          int m_in = mi * 16 + qd * 4 + r2 * 2;
          u32 p = pk2h(acc[mi][ei][r2 * 2], acc[mi][ei][r2 * 2 + 1]);
          *(u32*)&vbuf[e_in * 66 + m_in] = p;
        }
    __builtin_amdgcn_s_waitcnt(0); /* drain lgkm before wave-local readback */
    const int dbase = (e0 - 1024) + we;
    const int mb = (m0 & 2047) + wm;
    const int bb = m0 >> 11;
    u16* vt = Vt + (size_t)bb * (D_ * N_);
#pragma unroll
    for (int it = 0; it < 4; ++it) {
      int e_in = it * 16 + (lane >> 2);
      int mc = lane & 3;
      u32 q0[8];
#pragma unroll
      for (int c4 = 0; c4 < 8; ++c4)
        q0[c4] = *(const u32*)&vbuf[e_in * 66 + mc * 16 + c4 * 2];
      u16* gp = vt + (size_t)(dbase + e_in) * N_ + mb + mc * 16;
      *(u32x4*)gp = (u32x4){q0[0], q0[1], q0[2], q0[3]};
      *(u32x4*)(gp + 8) = (u32x4){q0[4], q0[5], q0[6], q0[7]};
    }
  }
}

/* ---------------- MFMA sliding-window attention (R11-proven, TQA=16) ------- */
#define TQA 16
#define SA 200
#define SP 208

__global__ __launch_bounds__(512) void attn_kernel(const u16* __restrict__ Qf,
                                                   const u16* __restrict__ Kf,
                                                   const u16* __restrict__ Vt,
                                                   float* __restrict__ Out) {
  const int m0 = blockIdx.x * TQA;
  const int b = m0 >> 11;
  const int n0 = m0 & 2047;
  const int t = threadIdx.x;
  const int lane = t & 63;
  const int w = t >> 6;
  const int qd = lane >> 4;
  const int l16 = lane & 15;

  __shared__ __align__(16) float att[2][TQA][SA];
  __shared__ __align__(16) u16 pS[TQA][SP];

  const int jw = w & 3;
  const int kh = w >> 2;
  const int ntm = (jw < 3) ? 3 : 1; /* col-tiles 0..9 only (160 cols) */

  /* Phase 1: logits = Q K^T, split-K across wave pairs. */
  f32x4 acc[3];
#pragma unroll
  for (int nt = 0; nt < 3; ++nt) acc[nt] = (f32x4){0.f, 0.f, 0.f, 0.f};

  const size_t qrow = (size_t)(m0 + l16) * D_ + qd * 8;
  for (int ks = kh * 8; ks < kh * 8 + 8; ++ks) {
    u16x8 qv = *(const u16x8*)(Qf + qrow + ks * 32);
#pragma unroll
    for (int nt = 0; nt < 3; ++nt) {
      if (nt < ntm) {
        int j = (jw * 3 + nt) * 16 + l16;
        int rl = n0 - 128 + j;
        int rg = b * N_ + (rl > 0 ? rl : 0);
        u16x8 kv = *(const u16x8*)(Kf + (size_t)rg * D_ + ks * 32 + qd * 8);
        acc[nt] = mfma_f16(qv, kv, acc[nt]);
      }
    }
  }
#pragma unroll
  for (int nt = 0; nt < 3; ++nt)
    if (nt < ntm) {
#pragma unroll
      for (int r = 0; r < 4; ++r)
        att[kh][qd * 4 + r][(jw * 3 + nt) * 16 + l16] = acc[nt][r];
    }
  __syncthreads();

  /* Phase 2: softmax per query i over j in [i+1, i+128]; 32 thr/row. */
  {
    const int i = t >> 5;
    const int c = t & 31;
    float ev[6];
    float mx = -1e30f;
#pragma unroll
    for (int s = 0; s < 6; ++s) {
      int j = c * 6 + s;
      bool inw = (j >= i + 1) && (j <= i + 128);
      float v = -1e30f;
      if (inw) v = (n0 - 128 + j < 0) ? 0.f : att[0][i][j] + att[1][i][j];
      ev[s] = v;
      mx = fmaxf(mx, v);
    }
    mx = fmaxf(mx, __shfl_xor(mx, 1));
    mx = fmaxf(mx, __shfl_xor(mx, 2));
    mx = fmaxf(mx, __shfl_xor(mx, 4));
    mx = fmaxf(mx, __shfl_xor(mx, 8));
    mx = fmaxf(mx, __shfl_xor(mx, 16));
    float sum = 0.f;
#pragma unroll
    for (int s = 0; s < 6; ++s) {
      ev[s] = (ev[s] > -1e29f) ? __expf(ev[s] - mx) : 0.f;
      sum += ev[s];
    }
    sum += __shfl_xor(sum, 1);
    sum += __shfl_xor(sum, 2);
    sum += __shfl_xor(sum, 4);
    sum += __shfl_xor(sum, 8);
    sum += __shfl_xor(sum, 16);
    const float inv = 1.f / sum;
#pragma unroll
    for (int s = 0; s < 6; ++s) {
      int j = c * 6 + s;
      bool zv = (n0 - 128 + j) < 0;
      pS[i][j] = zv ? (u16)0 : f2h(ev[s] * inv);
    }
  }
  __syncthreads();

  /* Phase 3: Out = P V; wave w owns d-cols [w*64, w*64+64). kk<5. */
  f32x4 oacc[4];
#pragma unroll
  for (int nt = 0; nt < 4; ++nt) oacc[nt] = (f32x4){0.f, 0.f, 0.f, 0.f};

  const u16* vtb = Vt + (size_t)b * (D_ * N_);
  for (int kk = 0; kk < 5; ++kk) {
    u16x8 pa = *(const u16x8*)&pS[l16][kk * 32 + qd * 8];
    const int rl = n0 - 128 + kk * 32 + qd * 8; /* may be <0: P=0 guards */
#pragma unroll
    for (int nt = 0; nt < 4; ++nt) {
      int d = w * 64 + nt * 16 + l16;
      u16x8 vv = *(const u16x8*)(vtb + (size_t)d * N_ + rl);
      oacc[nt] = mfma_f16(pa, vv, oacc[nt]);
    }
  }
#pragma unroll
  for (int nt = 0; nt < 4; ++nt)
#pragma unroll
    for (int r = 0; r < 4; ++r)
      Out[(size_t)(m0 + qd * 4 + r) * D_ + w * 64 + nt * 16 + l16] = oacc[nt][r];
}

extern "C" void kernel_launch(void* const* d_in, const int* in_sizes, int n_in,
                              void* d_out, int out_size, void* d_ws, size_t ws_size,
                              hipStream_t stream) {
  const float* x = (const float*)d_in[0];
  const float* wl = (const float*)d_in[1];
  float* out = (float*)d_out;

  u16* Qf = (u16*)d_ws;
  u16* Kf = Qf + QK_ELEMS;
  u16* Vt = Kf + QK_ELEMS;

  dim3 g1(MTOT / TM, E3 / TE); /* 32 x 12 */
  qkv_gemm<<<g1, 256, 0, stream>>>(x, wl, Qf, Kf, Vt);
  attn_kernel<<<MTOT / TQA, 512, 0, stream>>>(Qf, Kf, Vt, out);
}

// Round 8
// 92.955 us; speedup vs baseline: 1.4382x; 1.0467x over previous
//
#include <hip/hip_runtime.h>
#include <cstdint>
#include <cstddef>

typedef unsigned short u16;
typedef unsigned int u32;
typedef u16 u16x4 __attribute__((ext_vector_type(4)));
typedef u16 u16x8 __attribute__((ext_vector_type(8)));
typedef u32 u32x2 __attribute__((ext_vector_type(2)));
typedef u32 u32x4 __attribute__((ext_vector_type(4)));
typedef _Float16 f16x8 __attribute__((ext_vector_type(8)));
typedef float f32x4 __attribute__((ext_vector_type(4)));

#define B_   2
#define N_   2048
#define F_   512
#define D_   512
#define W_   128
#define E3   1536
#define MTOT 4096
#define QK_ELEMS (MTOT * D_) /* 2,097,152 */

/* ===== R17 =====
 * R16 post-mortem: GEMM 2-deep prefetch regressed (+2.8 us; VGPR-pressure /
 * longer tail > latency hidden). GEMM reverted to the R11 1-deep version
 * (94.49 us baseline) and declared at-structure-ceiling (~405 TF == the
 * measured reg-staged 128^2 ceiling at this shape).
 * New single variable: XCD-aware block swizzle in attn (T1). Neighboring
 * blocks share 128/144 of their K/V window rows, but default dispatch
 * round-robins consecutive blocks across the 8 per-XCD L2s -> each XCD
 * re-fetches the sliding windows (~88 MB total vs ~12 MB unique; matches
 * attn's 19.6 us). Swizzle logical = (bid%8)*32 + bid/8 gives each XCD a
 * contiguous run of 32 Q-tiles (512 positions + 144 halo ~= 1.9 MB < 4 MB
 * L2) -> HBM fetch collapses toward the unique-data floor. */

__device__ __forceinline__ u16 f2h(float f) {
  return __builtin_bit_cast(u16, (_Float16)f); /* v_cvt_f16_f32, RNE */
}
__device__ __forceinline__ u32 pk2h(float a, float b) {
  return __builtin_bit_cast(u32, __builtin_amdgcn_cvt_pkrtz(a, b));
}
__device__ __forceinline__ f32x4 mfma_f16(u16x8 a, u16x8 b, f32x4 c) {
  return __builtin_amdgcn_mfma_f32_16x16x32_f16(
      __builtin_bit_cast(f16x8, a), __builtin_bit_cast(f16x8, b), c, 0, 0, 0);
}

/* ---------------- QKV GEMM, fused fp32->fp16 reg-staged (R11, proven) ------ */
#define TM 128
#define TE 128
#define BK 32
#define NK (F_ / BK) /* 16 */

__global__ __launch_bounds__(256) void qkv_gemm(const float* __restrict__ X,
                                                const float* __restrict__ Wl,
                                                u16* __restrict__ Qf,
                                                u16* __restrict__ Kf,
                                                u16* __restrict__ Vt) {
  __shared__ __align__(16) u16 smem[16896]; /* dbuf 2x8192 u16; vbuf 4x8448 B */

  const int tid = threadIdx.x;
  const int m0 = blockIdx.x * TM;
  const int e0 = blockIdx.y * TE;
  const int lane = tid & 63;
  const int wave = tid >> 6;
  const int wm = (wave >> 1) * 64;
  const int we = (wave & 1) * 64;
  const int qd = lane >> 4;
  const int l16 = lane & 15;

  const int r0 = wave * 32;
  const int sr = lane >> 2; /* 0..15 */
  const int sc = lane & 3;  /* src chunk */
  const int key = (sr >> 1) & 3;
  const int cl = sc ^ key; /* LDS chunk */
  const int la = (r0 + sr) * 32 + cl * 8; /* u16 offset within a buffer half */

  const float* ga = X + (size_t)(m0 + r0 + sr) * F_ + sc * 8;
  const float* gb = Wl + (size_t)(e0 + r0 + sr) * F_ + sc * 8;

  f32x4 acc[4][4];
#pragma unroll
  for (int i = 0; i < 4; ++i)
#pragma unroll
    for (int j = 0; j < 4; ++j) acc[i][j] = (f32x4){0.f, 0.f, 0.f, 0.f};

  const int swz = (l16 >> 1) & 3;
  const int rdoff = (qd ^ swz) * 8; /* R6-proven read swizzle */

  /* Prologue: stage k=0 into buf0. */
  {
    float4 a0 = *(const float4*)(ga);
    float4 a1 = *(const float4*)(ga + 4);
    float4 a2 = *(const float4*)(ga + 16 * F_);
    float4 a3 = *(const float4*)(ga + 16 * F_ + 4);
    float4 b0 = *(const float4*)(gb);
    float4 b1 = *(const float4*)(gb + 4);
    float4 b2 = *(const float4*)(gb + 16 * F_);
    float4 b3 = *(const float4*)(gb + 16 * F_ + 4);
    u16* sA = smem;
    u16* sB = smem + 4096;
    *(u32x4*)&sA[la] = (u32x4){pk2h(a0.x, a0.y), pk2h(a0.z, a0.w),
                               pk2h(a1.x, a1.y), pk2h(a1.z, a1.w)};
    *(u32x4*)&sA[la + 512] = (u32x4){pk2h(a2.x, a2.y), pk2h(a2.z, a2.w),
                                     pk2h(a3.x, a3.y), pk2h(a3.z, a3.w)};
    *(u32x4*)&sB[la] = (u32x4){pk2h(b0.x, b0.y), pk2h(b0.z, b0.w),
                               pk2h(b1.x, b1.y), pk2h(b1.z, b1.w)};
    *(u32x4*)&sB[la + 512] = (u32x4){pk2h(b2.x, b2.y), pk2h(b2.z, b2.w),
                                     pk2h(b3.x, b3.y), pk2h(b3.z, b3.w)};
  }

  for (int k = 0; k < NK; ++k) {
    u16* sAk = smem + (k & 1) * 8192;
    u16* sBk = sAk + 4096;
    __syncthreads();

    u16x8 fA[4], fB[4];
#pragma unroll
    for (int mi = 0; mi < 4; ++mi)
      fA[mi] = *(const u16x8*)&sAk[(wm + mi * 16 + l16) * 32 + rdoff];
#pragma unroll
    for (int ei = 0; ei < 4; ++ei)
      fB[ei] = *(const u16x8*)&sBk[(we + ei * 16 + l16) * 32 + rdoff];

    /* Issue next tile's loads NOW; consumed after the MFMAs below. */
    float4 a0, a1, a2, a3, b0, b1, b2, b3;
    if (k + 1 < NK) {
      const float* gan = ga + (k + 1) * BK;
      const float* gbn = gb + (k + 1) * BK;
      a0 = *(const float4*)(gan);
      a1 = *(const float4*)(gan + 4);
      a2 = *(const float4*)(gan + 16 * F_);
      a3 = *(const float4*)(gan + 16 * F_ + 4);
      b0 = *(const float4*)(gbn);
      b1 = *(const float4*)(gbn + 4);
      b2 = *(const float4*)(gbn + 16 * F_);
      b3 = *(const float4*)(gbn + 16 * F_ + 4);
    }

#pragma unroll
    for (int mi = 0; mi < 4; ++mi)
#pragma unroll
      for (int ei = 0; ei < 4; ++ei)
        acc[mi][ei] = mfma_f16(fA[mi], fB[ei], acc[mi][ei]);

    if (k + 1 < NK) {
      u16* nA = smem + ((k + 1) & 1) * 8192;
      u16* nB = nA + 4096;
      *(u32x4*)&nA[la] = (u32x4){pk2h(a0.x, a0.y), pk2h(a0.z, a0.w),
                                 pk2h(a1.x, a1.y), pk2h(a1.z, a1.w)};
      *(u32x4*)&nA[la + 512] = (u32x4){pk2h(a2.x, a2.y), pk2h(a2.z, a2.w),
                                       pk2h(a3.x, a3.y), pk2h(a3.z, a3.w)};
      *(u32x4*)&nB[la] = (u32x4){pk2h(b0.x, b0.y), pk2h(b0.z, b0.w),
                                 pk2h(b1.x, b1.y), pk2h(b1.z, b1.w)};
      *(u32x4*)&nB[la + 512] = (u32x4){pk2h(b2.x, b2.y), pk2h(b2.z, b2.w),
                                       pk2h(b3.x, b3.y), pk2h(b3.z, b3.w)};
    }
  }

  /* C/D layout: row = qd*4 + reg, col = lane&15 */
  const int third = e0 >> 9; /* 0=Q, 1=K, 2=V */
  if (third < 2) {
    u16* P = third ? Kf : Qf;
    const int ecol0 = (e0 & 511) + we;
    const int odd = l16 & 1;
#pragma unroll
    for (int mi = 0; mi < 4; ++mi)
#pragma unroll
      for (int ei = 0; ei < 4; ++ei) {
        float x0 = acc[mi][ei][0], x1 = acc[mi][ei][1];
        float x2 = acc[mi][ei][2], x3 = acc[mi][ei][3];
        float t0 = __shfl_xor(x0, 1), t1 = __shfl_xor(x1, 1);
        float t2 = __shfl_xor(x2, 1), t3 = __shfl_xor(x3, 1);
        u32 pa = odd ? pk2h(t2, x2) : pk2h(x0, t0);
        u32 pb = odd ? pk2h(t3, x3) : pk2h(x1, t1);
        int mrow = m0 + wm + mi * 16 + qd * 4 + odd * 2;
        int colp = ecol0 + ei * 16 + (l16 & ~1);
        *(u32*)(P + (size_t)mrow * D_ + colp) = pa;
        *(u32*)(P + (size_t)(mrow + 1) * D_ + colp) = pb;
      }
  } else {
    /* V: per-wave 64x64 LDS transpose (stride 66 u16), coalesced Vt write. */
    __syncthreads();
    u16* vbuf = smem + wave * 4224; /* [64][66] u16 */
#pragma unroll
    for (int mi = 0; mi < 4; ++mi)
#pragma unroll
      for (int ei = 0; ei < 4; ++ei)
#pragma unroll
        for (int r2 = 0; r2 < 2; ++r2) {
          int e_in = ei * 16 + l16;
          int m_in = mi * 16 + qd * 4 + r2 * 2;
          u32 p = pk2h(acc[mi][ei][r2 * 2], acc[mi][ei][r2 * 2 + 1]);
          *(u32*)&vbuf[e_in * 66 + m_in] = p;
        }
    __builtin_amdgcn_s_waitcnt(0); /* drain lgkm before wave-local readback */
    const int dbase = (e0 - 1024) + we;
    const int mb = (m0 & 2047) + wm;
    const int bb = m0 >> 11;
    u16* vt = Vt + (size_t)bb * (D_ * N_);
#pragma unroll
    for (int it = 0; it < 4; ++it) {
      int e_in = it * 16 + (lane >> 2);
      int mc = lane & 3;
      u32 q0[8];
#pragma unroll
      for (int c4 = 0; c4 < 8; ++c4)
        q0[c4] = *(const u32*)&vbuf[e_in * 66 + mc * 16 + c4 * 2];
      u16* gp = vt + (size_t)(dbase + e_in) * N_ + mb + mc * 16;
      *(u32x4*)gp = (u32x4){q0[0], q0[1], q0[2], q0[3]};
      *(u32x4*)(gp + 8) = (u32x4){q0[4], q0[5], q0[6], q0[7]};
    }
  }
}

/* ---------------- MFMA sliding-window attention (R11 + XCD swizzle) -------- */
#define TQA 16
#define SA 200
#define SP 208
#define NWG_A (MTOT / TQA) /* 256 */
#define CPX (NWG_A / 8)    /* 32 blocks per XCD chunk */

__global__ __launch_bounds__(512) void attn_kernel(const u16* __restrict__ Qf,
                                                   const u16* __restrict__ Kf,
                                                   const u16* __restrict__ Vt,
                                                   float* __restrict__ Out) {
  /* T1 XCD swizzle: consecutive HW blocks land on different XCDs (round
   * robin); remap so XCD x processes logical tiles [x*32, x*32+32) --
   * contiguous sequence positions whose K/V windows overlap -> L2-resident. */
  const int bid = ((int)blockIdx.x & 7) * CPX + ((int)blockIdx.x >> 3);
  const int m0 = bid * TQA;
  const int b = m0 >> 11;
  const int n0 = m0 & 2047;
  const int t = threadIdx.x;
  const int lane = t & 63;
  const int w = t >> 6;
  const int qd = lane >> 4;
  const int l16 = lane & 15;

  __shared__ __align__(16) float att[2][TQA][SA];
  __shared__ __align__(16) u16 pS[TQA][SP];

  const int jw = w & 3;
  const int kh = w >> 2;
  const int ntm = (jw < 3) ? 3 : 1; /* col-tiles 0..9 only (160 cols) */

  /* Phase 1: logits = Q K^T, split-K across wave pairs. */
  f32x4 acc[3];
#pragma unroll
  for (int nt = 0; nt < 3; ++nt) acc[nt] = (f32x4){0.f, 0.f, 0.f, 0.f};

  const size_t qrow = (size_t)(m0 + l16) * D_ + qd * 8;
  for (int ks = kh * 8; ks < kh * 8 + 8; ++ks) {
    u16x8 qv = *(const u16x8*)(Qf + qrow + ks * 32);
#pragma unroll
    for (int nt = 0; nt < 3; ++nt) {
      if (nt < ntm) {
        int j = (jw * 3 + nt) * 16 + l16;
        int rl = n0 - 128 + j;
        int rg = b * N_ + (rl > 0 ? rl : 0);
        u16x8 kv = *(const u16x8*)(Kf + (size_t)rg * D_ + ks * 32 + qd * 8);
        acc[nt] = mfma_f16(qv, kv, acc[nt]);
      }
    }
  }
#pragma unroll
  for (int nt = 0; nt < 3; ++nt)
    if (nt < ntm) {
#pragma unroll
      for (int r = 0; r < 4; ++r)
        att[kh][qd * 4 + r][(jw * 3 + nt) * 16 + l16] = acc[nt][r];
    }
  __syncthreads();

  /* Phase 2: softmax per query i over j in [i+1, i+128]; 32 thr/row. */
  {
    const int i = t >> 5;
    const int c = t & 31;
    float ev[6];
    float mx = -1e30f;
#pragma unroll
    for (int s = 0; s < 6; ++s) {
      int j = c * 6 + s;
      bool inw = (j >= i + 1) && (j <= i + 128);
      float v = -1e30f;
      if (inw) v = (n0 - 128 + j < 0) ? 0.f : att[0][i][j] + att[1][i][j];
      ev[s] = v;
      mx = fmaxf(mx, v);
    }
    mx = fmaxf(mx, __shfl_xor(mx, 1));
    mx = fmaxf(mx, __shfl_xor(mx, 2));
    mx = fmaxf(mx, __shfl_xor(mx, 4));
    mx = fmaxf(mx, __shfl_xor(mx, 8));
    mx = fmaxf(mx, __shfl_xor(mx, 16));
    float sum = 0.f;
#pragma unroll
    for (int s = 0; s < 6; ++s) {
      ev[s] = (ev[s] > -1e29f) ? __expf(ev[s] - mx) : 0.f;
      sum += ev[s];
    }
    sum += __shfl_xor(sum, 1);
    sum += __shfl_xor(sum, 2);
    sum += __shfl_xor(sum, 4);
    sum += __shfl_xor(sum, 8);
    sum += __shfl_xor(sum, 16);
    const float inv = 1.f / sum;
#pragma unroll
    for (int s = 0; s < 6; ++s) {
      int j = c * 6 + s;
      bool zv = (n0 - 128 + j) < 0;
      pS[i][j] = zv ? (u16)0 : f2h(ev[s] * inv);
    }
  }
  __syncthreads();

  /* Phase 3: Out = P V; wave w owns d-cols [w*64, w*64+64). kk<5. */
  f32x4 oacc[4];
#pragma unroll
  for (int nt = 0; nt < 4; ++nt) oacc[nt] = (f32x4){0.f, 0.f, 0.f, 0.f};

  const u16* vtb = Vt + (size_t)b * (D_ * N_);
  for (int kk = 0; kk < 5; ++kk) {
    u16x8 pa = *(const u16x8*)&pS[l16][kk * 32 + qd * 8];
    const int rl = n0 - 128 + kk * 32 + qd * 8; /* may be <0: P=0 guards */
#pragma unroll
    for (int nt = 0; nt < 4; ++nt) {
      int d = w * 64 + nt * 16 + l16;
      u16x8 vv = *(const u16x8*)(vtb + (size_t)d * N_ + rl);
      oacc[nt] = mfma_f16(pa, vv, oacc[nt]);
    }
  }
#pragma unroll
  for (int nt = 0; nt < 4; ++nt)
#pragma unroll
    for (int r = 0; r < 4; ++r)
      Out[(size_t)(m0 + qd * 4 + r) * D_ + w * 64 + nt * 16 + l16] = oacc[nt][r];
}

extern "C" void kernel_launch(void* const* d_in, const int* in_sizes, int n_in,
                              void* d_out, int out_size, void* d_ws, size_t ws_size,
                              hipStream_t stream) {
  const float* x = (const float*)d_in[0];
  const float* wl = (const float*)d_in[1];
  float* out = (float*)d_out;

  u16* Qf = (u16*)d_ws;
  u16* Kf = Qf + QK_ELEMS;
  u16* Vt = Kf + QK_ELEMS;

  dim3 g1(MTOT / TM, E3 / TE); /* 32 x 12 */
  qkv_gemm<<<g1, 256, 0, stream>>>(x, wl, Qf, Kf, Vt);
  attn_kernel<<<MTOT / TQA, 512, 0, stream>>>(Qf, Kf, Vt, out);
}

// Round 9
// 91.904 us; speedup vs baseline: 1.4546x; 1.0114x over previous
//
#include <hip/hip_runtime.h>
#include <cstdint>
#include <cstddef>

typedef unsigned short u16;
typedef unsigned int u32;
typedef u16 u16x4 __attribute__((ext_vector_type(4)));
typedef u16 u16x8 __attribute__((ext_vector_type(8)));
typedef u32 u32x2 __attribute__((ext_vector_type(2)));
typedef u32 u32x4 __attribute__((ext_vector_type(4)));
typedef _Float16 f16x8 __attribute__((ext_vector_type(8)));
typedef float f32x4 __attribute__((ext_vector_type(4)));

#define B_   2
#define N_   2048
#define F_   512
#define D_   512
#define W_   128
#define E3   1536
#define MTOT 4096
#define QK_ELEMS (MTOT * D_) /* 2,097,152 */

/* ===== R18 =====
 * R17: XCD swizzle won (-1.5 us, 92.96). Remaining attn gap is latency
 * exposure at 2 waves/SIMD (256 blocks = 1 block/CU x 8 waves).
 * This round: attn block 512 -> 1024 threads (16 waves), SAME grid and SAME
 * total work (R15's mistake was shrinking the Q-tile, doubling window work):
 *  - phase 1: split-K 4-way (kh=w>>2, 4 ks each) x col 4-way -> 12 MFMA/wave
 *  - phase 2: one wave per query row, 64-lane reduce, sums 4 partials
 *  - phase 3: wave owns 32 d-cols -> 10 MFMA/wave
 *  - LDS 57.9 KB, 4 waves/SIMD -> ~4x issue overlap per latency window
 * GEMM unchanged (R11-proven); XCD swizzle kept. */

__device__ __forceinline__ u16 f2h(float f) {
  return __builtin_bit_cast(u16, (_Float16)f); /* v_cvt_f16_f32, RNE */
}
__device__ __forceinline__ u32 pk2h(float a, float b) {
  return __builtin_bit_cast(u32, __builtin_amdgcn_cvt_pkrtz(a, b));
}
__device__ __forceinline__ f32x4 mfma_f16(u16x8 a, u16x8 b, f32x4 c) {
  return __builtin_amdgcn_mfma_f32_16x16x32_f16(
      __builtin_bit_cast(f16x8, a), __builtin_bit_cast(f16x8, b), c, 0, 0, 0);
}

/* ---------------- QKV GEMM, fused fp32->fp16 reg-staged (R11, proven) ------ */
#define TM 128
#define TE 128
#define BK 32
#define NK (F_ / BK) /* 16 */

__global__ __launch_bounds__(256) void qkv_gemm(const float* __restrict__ X,
                                                const float* __restrict__ Wl,
                                                u16* __restrict__ Qf,
                                                u16* __restrict__ Kf,
                                                u16* __restrict__ Vt) {
  __shared__ __align__(16) u16 smem[16896]; /* dbuf 2x8192 u16; vbuf 4x8448 B */

  const int tid = threadIdx.x;
  const int m0 = blockIdx.x * TM;
  const int e0 = blockIdx.y * TE;
  const int lane = tid & 63;
  const int wave = tid >> 6;
  const int wm = (wave >> 1) * 64;
  const int we = (wave & 1) * 64;
  const int qd = lane >> 4;
  const int l16 = lane & 15;

  const int r0 = wave * 32;
  const int sr = lane >> 2; /* 0..15 */
  const int sc = lane & 3;  /* src chunk */
  const int key = (sr >> 1) & 3;
  const int cl = sc ^ key; /* LDS chunk */
  const int la = (r0 + sr) * 32 + cl * 8; /* u16 offset within a buffer half */

  const float* ga = X + (size_t)(m0 + r0 + sr) * F_ + sc * 8;
  const float* gb = Wl + (size_t)(e0 + r0 + sr) * F_ + sc * 8;

  f32x4 acc[4][4];
#pragma unroll
  for (int i = 0; i < 4; ++i)
#pragma unroll
    for (int j = 0; j < 4; ++j) acc[i][j] = (f32x4){0.f, 0.f, 0.f, 0.f};

  const int swz = (l16 >> 1) & 3;
  const int rdoff = (qd ^ swz) * 8; /* R6-proven read swizzle */

  /* Prologue: stage k=0 into buf0. */
  {
    float4 a0 = *(const float4*)(ga);
    float4 a1 = *(const float4*)(ga + 4);
    float4 a2 = *(const float4*)(ga + 16 * F_);
    float4 a3 = *(const float4*)(ga + 16 * F_ + 4);
    float4 b0 = *(const float4*)(gb);
    float4 b1 = *(const float4*)(gb + 4);
    float4 b2 = *(const float4*)(gb + 16 * F_);
    float4 b3 = *(const float4*)(gb + 16 * F_ + 4);
    u16* sA = smem;
    u16* sB = smem + 4096;
    *(u32x4*)&sA[la] = (u32x4){pk2h(a0.x, a0.y), pk2h(a0.z, a0.w),
                               pk2h(a1.x, a1.y), pk2h(a1.z, a1.w)};
    *(u32x4*)&sA[la + 512] = (u32x4){pk2h(a2.x, a2.y), pk2h(a2.z, a2.w),
                                     pk2h(a3.x, a3.y), pk2h(a3.z, a3.w)};
    *(u32x4*)&sB[la] = (u32x4){pk2h(b0.x, b0.y), pk2h(b0.z, b0.w),
                               pk2h(b1.x, b1.y), pk2h(b1.z, b1.w)};
    *(u32x4*)&sB[la + 512] = (u32x4){pk2h(b2.x, b2.y), pk2h(b2.z, b2.w),
                                     pk2h(b3.x, b3.y), pk2h(b3.z, b3.w)};
  }

  for (int k = 0; k < NK; ++k) {
    u16* sAk = smem + (k & 1) * 8192;
    u16* sBk = sAk + 4096;
    __syncthreads();

    u16x8 fA[4], fB[4];
#pragma unroll
    for (int mi = 0; mi < 4; ++mi)
      fA[mi] = *(const u16x8*)&sAk[(wm + mi * 16 + l16) * 32 + rdoff];
#pragma unroll
    for (int ei = 0; ei < 4; ++ei)
      fB[ei] = *(const u16x8*)&sBk[(we + ei * 16 + l16) * 32 + rdoff];

    /* Issue next tile's loads NOW; consumed after the MFMAs below. */
    float4 a0, a1, a2, a3, b0, b1, b2, b3;
    if (k + 1 < NK) {
      const float* gan = ga + (k + 1) * BK;
      const float* gbn = gb + (k + 1) * BK;
      a0 = *(const float4*)(gan);
      a1 = *(const float4*)(gan + 4);
      a2 = *(const float4*)(gan + 16 * F_);
      a3 = *(const float4*)(gan + 16 * F_ + 4);
      b0 = *(const float4*)(gbn);
      b1 = *(const float4*)(gbn + 4);
      b2 = *(const float4*)(gbn + 16 * F_);
      b3 = *(const float4*)(gbn + 16 * F_ + 4);
    }

#pragma unroll
    for (int mi = 0; mi < 4; ++mi)
#pragma unroll
      for (int ei = 0; ei < 4; ++ei)
        acc[mi][ei] = mfma_f16(fA[mi], fB[ei], acc[mi][ei]);

    if (k + 1 < NK) {
      u16* nA = smem + ((k + 1) & 1) * 8192;
      u16* nB = nA + 4096;
      *(u32x4*)&nA[la] = (u32x4){pk2h(a0.x, a0.y), pk2h(a0.z, a0.w),
                                 pk2h(a1.x, a1.y), pk2h(a1.z, a1.w)};
      *(u32x4*)&nA[la + 512] = (u32x4){pk2h(a2.x, a2.y), pk2h(a2.z, a2.w),
                                       pk2h(a3.x, a3.y), pk2h(a3.z, a3.w)};
      *(u32x4*)&nB[la] = (u32x4){pk2h(b0.x, b0.y), pk2h(b0.z, b0.w),
                                 pk2h(b1.x, b1.y), pk2h(b1.z, b1.w)};
      *(u32x4*)&nB[la + 512] = (u32x4){pk2h(b2.x, b2.y), pk2h(b2.z, b2.w),
                                       pk2h(b3.x, b3.y), pk2h(b3.z, b3.w)};
    }
  }

  /* C/D layout: row = qd*4 + reg, col = lane&15 */
  const int third = e0 >> 9; /* 0=Q, 1=K, 2=V */
  if (third < 2) {
    u16* P = third ? Kf : Qf;
    const int ecol0 = (e0 & 511) + we;
    const int odd = l16 & 1;
#pragma unroll
    for (int mi = 0; mi < 4; ++mi)
#pragma unroll
      for (int ei = 0; ei < 4; ++ei) {
        float x0 = acc[mi][ei][0], x1 = acc[mi][ei][1];
        float x2 = acc[mi][ei][2], x3 = acc[mi][ei][3];
        float t0 = __shfl_xor(x0, 1), t1 = __shfl_xor(x1, 1);
        float t2 = __shfl_xor(x2, 1), t3 = __shfl_xor(x3, 1);
        u32 pa = odd ? pk2h(t2, x2) : pk2h(x0, t0);
        u32 pb = odd ? pk2h(t3, x3) : pk2h(x1, t1);
        int mrow = m0 + wm + mi * 16 + qd * 4 + odd * 2;
        int colp = ecol0 + ei * 16 + (l16 & ~1);
        *(u32*)(P + (size_t)mrow * D_ + colp) = pa;
        *(u32*)(P + (size_t)(mrow + 1) * D_ + colp) = pb;
      }
  } else {
    /* V: per-wave 64x64 LDS transpose (stride 66 u16), coalesced Vt write. */
    __syncthreads();
    u16* vbuf = smem + wave * 4224; /* [64][66] u16 */
#pragma unroll
    for (int mi = 0; mi < 4; ++mi)
#pragma unroll
      for (int ei = 0; ei < 4; ++ei)
#pragma unroll
        for (int r2 = 0; r2 < 2; ++r2) {
          int e_in = ei * 16 + l16;
          int m_in = mi * 16 + qd * 4 + r2 * 2;
          u32 p = pk2h(acc[mi][ei][r2 * 2], acc[mi][ei][r2 * 2 + 1]);
          *(u32*)&vbuf[e_in * 66 + m_in] = p;
        }
    __builtin_amdgcn_s_waitcnt(0); /* drain lgkm before wave-local readback */
    const int dbase = (e0 - 1024) + we;
    const int mb = (m0 & 2047) + wm;
    const int bb = m0 >> 11;
    u16* vt = Vt + (size_t)bb * (D_ * N_);
#pragma unroll
    for (int it = 0; it < 4; ++it) {
      int e_in = it * 16 + (lane >> 2);
      int mc = lane & 3;
      u32 q0[8];
#pragma unroll
      for (int c4 = 0; c4 < 8; ++c4)
        q0[c4] = *(const u32*)&vbuf[e_in * 66 + mc * 16 + c4 * 2];
      u16* gp = vt + (size_t)(dbase + e_in) * N_ + mb + mc * 16;
      *(u32x4*)gp = (u32x4){q0[0], q0[1], q0[2], q0[3]};
      *(u32x4*)(gp + 8) = (u32x4){q0[4], q0[5], q0[6], q0[7]};
    }
  }
}

/* ---------------- MFMA sliding-window attention (R18: 16 waves) ------------
 * 256 blocks x 1024 threads. Work per block identical to R11/R17 (TQA=16,
 * 10 col-tiles, kk<5); partitioned over 16 waves instead of 8.
 * Phase 1: kh = w>>2 (4-way split-K, 4 ks each), jw = w&3 (ntm 3/3/3/1).
 * Phase 2: wave w owns query row w; 64-lane reduce; sums att[0..3].
 * Phase 3: wave w owns d-cols [w*32, w*32+32), nt<2.
 * XCD swizzle (R17-proven) kept. */
#define TQA 16
#define SA 200
#define SP 208
#define NWG_A (MTOT / TQA) /* 256 */
#define CPX (NWG_A / 8)    /* 32 blocks per XCD chunk */

__global__ __launch_bounds__(1024) void attn_kernel(const u16* __restrict__ Qf,
                                                    const u16* __restrict__ Kf,
                                                    const u16* __restrict__ Vt,
                                                    float* __restrict__ Out) {
  const int bid = ((int)blockIdx.x & 7) * CPX + ((int)blockIdx.x >> 3);
  const int m0 = bid * TQA;
  const int b = m0 >> 11;
  const int n0 = m0 & 2047;
  const int t = threadIdx.x;
  const int lane = t & 63;
  const int w = t >> 6; /* 0..15 */
  const int qd = lane >> 4;
  const int l16 = lane & 15;

  __shared__ __align__(16) float att[4][TQA][SA]; /* 51.2 KB */
  __shared__ __align__(16) u16 pS[TQA][SP];       /* 6.7 KB */

  const int jw = w & 3;
  const int kh = w >> 2; /* 0..3 */
  const int ntm = (jw < 3) ? 3 : 1; /* col-tiles 0..9 (160 cols) */

  /* Phase 1: logits = Q K^T; split-K 4-way x col-split 4-way. */
  f32x4 acc[3];
#pragma unroll
  for (int nt = 0; nt < 3; ++nt) acc[nt] = (f32x4){0.f, 0.f, 0.f, 0.f};

  const size_t qrow = (size_t)(m0 + l16) * D_ + qd * 8;
  for (int ks = kh * 4; ks < kh * 4 + 4; ++ks) {
    u16x8 qv = *(const u16x8*)(Qf + qrow + ks * 32);
#pragma unroll
    for (int nt = 0; nt < 3; ++nt) {
      if (nt < ntm) {
        int j = (jw * 3 + nt) * 16 + l16;
        int rl = n0 - 128 + j;
        int rg = b * N_ + (rl > 0 ? rl : 0);
        u16x8 kv = *(const u16x8*)(Kf + (size_t)rg * D_ + ks * 32 + qd * 8);
        acc[nt] = mfma_f16(qv, kv, acc[nt]);
      }
    }
  }
#pragma unroll
  for (int nt = 0; nt < 3; ++nt)
    if (nt < ntm) {
#pragma unroll
      for (int r = 0; r < 4; ++r)
        att[kh][qd * 4 + r][(jw * 3 + nt) * 16 + l16] = acc[nt][r];
    }
  __syncthreads();

  /* Phase 2: softmax; wave w owns query row i=w; 64 lanes, 3 cols each. */
  {
    const int i = w;
    const int c = lane;
    float ev[3];
    float mx = -1e30f;
#pragma unroll
    for (int s = 0; s < 3; ++s) {
      int j = c + s * 64;
      bool inw = (j >= i + 1) && (j <= i + 128);
      float v = -1e30f;
      if (inw)
        v = (n0 - 128 + j < 0)
                ? 0.f
                : att[0][i][j] + att[1][i][j] + att[2][i][j] + att[3][i][j];
      ev[s] = v;
      mx = fmaxf(mx, v);
    }
    mx = fmaxf(mx, __shfl_xor(mx, 1));
    mx = fmaxf(mx, __shfl_xor(mx, 2));
    mx = fmaxf(mx, __shfl_xor(mx, 4));
    mx = fmaxf(mx, __shfl_xor(mx, 8));
    mx = fmaxf(mx, __shfl_xor(mx, 16));
    mx = fmaxf(mx, __shfl_xor(mx, 32));
    float sum = 0.f;
#pragma unroll
    for (int s = 0; s < 3; ++s) {
      ev[s] = (ev[s] > -1e29f) ? __expf(ev[s] - mx) : 0.f;
      sum += ev[s];
    }
    sum += __shfl_xor(sum, 1);
    sum += __shfl_xor(sum, 2);
    sum += __shfl_xor(sum, 4);
    sum += __shfl_xor(sum, 8);
    sum += __shfl_xor(sum, 16);
    sum += __shfl_xor(sum, 32);
    const float inv = 1.f / sum;
#pragma unroll
    for (int s = 0; s < 3; ++s) {
      int j = c + s * 64;
      if (j < 160) {
        bool zv = (n0 - 128 + j) < 0;
        pS[i][j] = zv ? (u16)0 : f2h(ev[s] * inv);
      }
    }
  }
  __syncthreads();

  /* Phase 3: Out = P V; wave w owns d-cols [w*32, w*32+32). kk<5. */
  f32x4 oacc[2];
#pragma unroll
  for (int nt = 0; nt < 2; ++nt) oacc[nt] = (f32x4){0.f, 0.f, 0.f, 0.f};

  const u16* vtb = Vt + (size_t)b * (D_ * N_);
  for (int kk = 0; kk < 5; ++kk) {
    u16x8 pa = *(const u16x8*)&pS[l16][kk * 32 + qd * 8];
    const int rl = n0 - 128 + kk * 32 + qd * 8; /* may be <0: P=0 guards */
#pragma unroll
    for (int nt = 0; nt < 2; ++nt) {
      int d = w * 32 + nt * 16 + l16;
      u16x8 vv = *(const u16x8*)(vtb + (size_t)d * N_ + rl);
      oacc[nt] = mfma_f16(pa, vv, oacc[nt]);
    }
  }
#pragma unroll
  for (int nt = 0; nt < 2; ++nt)
#pragma unroll
    for (int r = 0; r < 4; ++r)
      Out[(size_t)(m0 + qd * 4 + r) * D_ + w * 32 + nt * 16 + l16] = oacc[nt][r];
}

extern "C" void kernel_launch(void* const* d_in, const int* in_sizes, int n_in,
                              void* d_out, int out_size, void* d_ws, size_t ws_size,
                              hipStream_t stream) {
  const float* x = (const float*)d_in[0];
  const float* wl = (const float*)d_in[1];
  float* out = (float*)d_out;

  u16* Qf = (u16*)d_ws;
  u16* Kf = Qf + QK_ELEMS;
  u16* Vt = Kf + QK_ELEMS;

  dim3 g1(MTOT / TM, E3 / TE); /* 32 x 12 */
  qkv_gemm<<<g1, 256, 0, stream>>>(x, wl, Qf, Kf, Vt);
  attn_kernel<<<MTOT / TQA, 1024, 0, stream>>>(Qf, Kf, Vt, out);
}